// Round 4
// baseline (35.864 us; speedup 1.0000x reference)
//
#include <hip/hip_runtime.h>

#define PI_F 3.14159265358979323846f

constexpr int ED = 128;     // embed_dim
constexpr int NPH = 20;     // sin(0.1*pi*p) for integer p has exact period 20
constexpr int NCHARS = 95;
constexpr int NCOMBO = NCHARS * NPH;  // 1900 distinct output rows

typedef float f4 __attribute__((ext_vector_type(4)));

// ---- build: one wave per (char, phase) combo; 475 blocks x 4 waves = 1900
__global__ __launch_bounds__(256) void build_psi(
    const float* __restrict__ W,
    float4* __restrict__ tbl)
{
    const int lane = threadIdx.x & 63;
    const int wv = threadIdx.x >> 6;
    const int combo = blockIdx.x * 4 + wv;   // grid is exact: 475*4 = 1900
    const int c = combo / NPH;
    const int ph = combo - c * NPH;

    const float* p = W + c * 8;
    const float omega = p[0] * 2.0f;
    const float A1 = p[1], A2 = p[2], A3 = p[3];
    const float beta = p[4];
    const float gamma = 1.0f / (1.0f + __expf(-p[5]));  // sigmoid
    const float phi = p[6] * PI_F;
    const float pos_phase = __sinf((float)ph * (0.1f * PI_F));

    float w01[2];
    #pragma unroll
    for (int k = 0; k < 2; ++k) {
        const float fj = (float)(lane + 64 * k);
        const float a = omega * fj + phi;
        const float sa = __sinf(a);
        const float ca = __cosf(a);
        // sin(2a)=2 sa ca ; sin(3a)=sa(3-4 sa^2)
        const float wave = (A1 * sa + A2 * (2.0f * sa * ca)
                            + A3 * sa * (3.0f - 4.0f * sa * sa))
                           * __expf(-gamma * fj);
        w01[k] = wave + beta * fj * pos_phase;
    }

    // roll(wave,1): prev[j] = wave[(j-1) & 127]
    const int lm1 = (lane + 63) & 63;
    const float u0 = __shfl(w01[0], lm1, 64);
    const float u1 = __shfl(w01[1], lm1, 64);
    const float prev0 = (lane == 0) ? u1 : u0;  // j=0  -> wave[127]
    const float prev1 = (lane == 0) ? u0 : u1;  // j=64 -> wave[63]

    const float4 o0 = make_float4(w01[0], prev0, __sinf(w01[0]), __cosf(w01[0]));
    const float4 o1 = make_float4(w01[1], prev1, __sinf(w01[1]), __cosf(w01[1]));
    tbl[(size_t)combo * ED + lane] = o0;
    tbl[(size_t)combo * ED + 64 + lane] = o1;
}

// ---- main: pure gather-copy, one wave per output row
__global__ __launch_bounds__(256) void ptok_copy(
    const int* __restrict__ char_idx,
    const int* __restrict__ positions,
    const f4* __restrict__ tbl,
    f4* __restrict__ out,
    int S)
{
    const int lane = threadIdx.x & 63;
    const int wv = threadIdx.x >> 6;
    const int row = blockIdx.x * 4 + wv;   // b*S + s
    const int s = row & (S - 1);           // S = 8192 (pow2)

    const int c = char_idx[row];           // wave-uniform
    int ph = positions[s] % NPH;           // exact: integer-period-20
    if (ph < 0) ph += NPH;

    const f4* trow = tbl + ((c * NPH + ph) << 7);
    f4* orow = out + ((size_t)row << 7);

    const f4 a = trow[lane];
    const f4 b = trow[64 + lane];
    __builtin_nontemporal_store(a, orow + lane);
    __builtin_nontemporal_store(b, orow + 64 + lane);
}

// ---- fallback (round-2 fused) in case ws_size is too small for the table
__global__ __launch_bounds__(256) void ptok_fused(
    const int* __restrict__ char_idx,
    const int* __restrict__ positions,
    const float* __restrict__ W,
    float* __restrict__ out,
    int S)
{
    const int lane = threadIdx.x & 63;
    const int wv = threadIdx.x >> 6;
    const int row = blockIdx.x * 4 + wv;
    const int s = row & (S - 1);

    const int c = char_idx[row];
    const float4 p0 = reinterpret_cast<const float4*>(W + c * 8)[0];
    const float4 p1 = reinterpret_cast<const float4*>(W + c * 8)[1];
    const float omega = p0.x * 2.0f;
    const float A1 = p0.y, A2 = p0.z, A3 = p0.w;
    const float beta = p1.x;
    const float gamma = 1.0f / (1.0f + __expf(-p1.y));
    const float phi = p1.z * PI_F;
    const float pos_phase = __sinf((float)positions[s] * (0.1f * PI_F));

    float w01[2];
    #pragma unroll
    for (int k = 0; k < 2; ++k) {
        const float fj = (float)(lane + 64 * k);
        const float a = omega * fj + phi;
        const float sa = __sinf(a);
        const float ca = __cosf(a);
        const float wave = (A1 * sa + A2 * (2.0f * sa * ca)
                            + A3 * sa * (3.0f - 4.0f * sa * sa))
                           * __expf(-gamma * fj);
        w01[k] = wave + beta * fj * pos_phase;
    }
    const int lm1 = (lane + 63) & 63;
    const float u0 = __shfl(w01[0], lm1, 64);
    const float u1 = __shfl(w01[1], lm1, 64);
    const float prev0 = (lane == 0) ? u1 : u0;
    const float prev1 = (lane == 0) ? u0 : u1;

    float4* orow = reinterpret_cast<float4*>(out) + (size_t)row * ED;
    float4 o0, o1;
    o0.x = w01[0]; o0.y = prev0; o0.z = __sinf(w01[0]); o0.w = __cosf(w01[0]);
    o1.x = w01[1]; o1.y = prev1; o1.z = __sinf(w01[1]); o1.w = __cosf(w01[1]);
    orow[lane] = o0;
    orow[64 + lane] = o1;
}

extern "C" void kernel_launch(void* const* d_in, const int* in_sizes, int n_in,
                              void* d_out, int out_size, void* d_ws, size_t ws_size,
                              hipStream_t stream) {
    const int* char_idx  = (const int*)d_in[0];   // [B*S]
    const int* positions = (const int*)d_in[1];   // [S]
    const float* W       = (const float*)d_in[2]; // [95, 8]

    const int nrows = in_sizes[0];                // B*S = 65536
    const int S = in_sizes[1];                    // 8192

    const size_t TBL_BYTES = (size_t)NCOMBO * ED * sizeof(float4);  // 3,891,200

    if (ws_size >= TBL_BYTES) {
        build_psi<<<NCOMBO / 4, 256, 0, stream>>>(W, (float4*)d_ws);
        ptok_copy<<<nrows / 4, 256, 0, stream>>>(
            char_idx, positions, (const f4*)d_ws, (f4*)d_out, S);
    } else {
        ptok_fused<<<nrows / 4, 256, 0, stream>>>(
            char_idx, positions, W, (float*)d_out, S);
    }
}

// Round 5
// 31.450 us; speedup vs baseline: 1.1404x; 1.1404x over previous
//
#include <hip/hip_runtime.h>

#define PI_F 3.14159265358979323846f

constexpr int ED = 128;     // embed_dim
constexpr int NCHARS = 95;
constexpr int NTBL = NCHARS * ED;  // 12160 entries

typedef float f4 __attribute__((ext_vector_type(4)));

// ---- build: tbl2[c][j] = (base, sin(base), cos(base), beta*j)   194,560 B
__global__ __launch_bounds__(256) void build_tbl2(
    const float* __restrict__ W,
    float4* __restrict__ tbl)
{
    const int i = blockIdx.x * 256 + threadIdx.x;
    if (i >= NTBL) return;
    const int c = i >> 7;          // i / 128
    const int j = i & (ED - 1);

    const float* p = W + c * 8;
    const float omega = p[0] * 2.0f;
    const float A1 = p[1], A2 = p[2], A3 = p[3];
    const float beta = p[4];
    const float gamma = 1.0f / (1.0f + __expf(-p[5]));  // sigmoid
    const float phi = p[6] * PI_F;

    const float fj = (float)j;
    const float a = omega * fj + phi;
    const float sa = __sinf(a);
    const float ca = __cosf(a);
    // sin(2a)=2 sa ca ; sin(3a)=sa(3-4 sa^2)
    const float base = (A1 * sa + A2 * (2.0f * sa * ca)
                        + A3 * sa * (3.0f - 4.0f * sa * sa))
                       * __expf(-gamma * fj);
    tbl[i] = make_float4(base, __sinf(base), __cosf(base), beta * fj);
}

// ---- main: 2 table loads + angle addition per element
__global__ __launch_bounds__(256) void ptok_main(
    const int* __restrict__ char_idx,
    const int* __restrict__ positions,
    const f4* __restrict__ tbl,
    f4* __restrict__ out,
    int S)
{
    const int lane = threadIdx.x & 63;
    const int wv = threadIdx.x >> 6;
    const int row = blockIdx.x * 4 + wv;    // b*S + s
    const int s = row & (S - 1);            // S = 8192 (pow2)

    const int c = char_idx[row];            // wave-uniform
    const float pp = __sinf((float)positions[s] * (0.1f * PI_F));  // uniform

    const f4 t0 = tbl[(c << 7) + lane];
    const f4 t1 = tbl[(c << 7) + 64 + lane];

    // w = base + (beta*j)*pp ; delta = (beta*j)*pp
    const float d0 = t0.w * pp;
    const float d1 = t1.w * pp;
    const float w0 = t0.x + d0;
    const float w1 = t1.x + d1;
    const float sd0 = __sinf(d0), cd0 = __cosf(d0);
    const float sd1 = __sinf(d1), cd1 = __cosf(d1);
    // sin(base+d), cos(base+d) via angle addition (t.y=sin base, t.z=cos base)
    const float sw0 = fmaf(t0.y, cd0, t0.z * sd0);
    const float cw0 = fmaf(t0.z, cd0, -t0.y * sd0);
    const float sw1 = fmaf(t1.y, cd1, t1.z * sd1);
    const float cw1 = fmaf(t1.z, cd1, -t1.y * sd1);

    // roll(wave,1): prev[j] = wave[(j-1) & 127]
    const int lm1 = (lane + 63) & 63;
    const float u0 = __shfl(w0, lm1, 64);
    const float u1 = __shfl(w1, lm1, 64);
    const float prev0 = (lane == 0) ? u1 : u0;  // j=0  -> wave[127]
    const float prev1 = (lane == 0) ? u0 : u1;  // j=64 -> wave[63]

    f4* orow = out + ((size_t)row << 7);
    f4 o0, o1;
    o0.x = w0; o0.y = prev0; o0.z = sw0; o0.w = cw0;
    o1.x = w1; o1.y = prev1; o1.z = sw1; o1.w = cw1;
    orow[lane] = o0;
    orow[64 + lane] = o1;
}

// ---- fallback (round-2 fused) if ws too small
__global__ __launch_bounds__(256) void ptok_fused(
    const int* __restrict__ char_idx,
    const int* __restrict__ positions,
    const float* __restrict__ W,
    float* __restrict__ out,
    int S)
{
    const int lane = threadIdx.x & 63;
    const int wv = threadIdx.x >> 6;
    const int row = blockIdx.x * 4 + wv;
    const int s = row & (S - 1);

    const int c = char_idx[row];
    const float4 p0 = reinterpret_cast<const float4*>(W + c * 8)[0];
    const float4 p1 = reinterpret_cast<const float4*>(W + c * 8)[1];
    const float omega = p0.x * 2.0f;
    const float A1 = p0.y, A2 = p0.z, A3 = p0.w;
    const float beta = p1.x;
    const float gamma = 1.0f / (1.0f + __expf(-p1.y));
    const float phi = p1.z * PI_F;
    const float pos_phase = __sinf((float)positions[s] * (0.1f * PI_F));

    float w01[2];
    #pragma unroll
    for (int k = 0; k < 2; ++k) {
        const float fj = (float)(lane + 64 * k);
        const float a = omega * fj + phi;
        const float sa = __sinf(a);
        const float ca = __cosf(a);
        const float wave = (A1 * sa + A2 * (2.0f * sa * ca)
                            + A3 * sa * (3.0f - 4.0f * sa * sa))
                           * __expf(-gamma * fj);
        w01[k] = wave + beta * fj * pos_phase;
    }
    const int lm1 = (lane + 63) & 63;
    const float u0 = __shfl(w01[0], lm1, 64);
    const float u1 = __shfl(w01[1], lm1, 64);
    const float prev0 = (lane == 0) ? u1 : u0;
    const float prev1 = (lane == 0) ? u0 : u1;

    float4* orow = reinterpret_cast<float4*>(out) + (size_t)row * ED;
    float4 o0, o1;
    o0.x = w01[0]; o0.y = prev0; o0.z = __sinf(w01[0]); o0.w = __cosf(w01[0]);
    o1.x = w01[1]; o1.y = prev1; o1.z = __sinf(w01[1]); o1.w = __cosf(w01[1]);
    orow[lane] = o0;
    orow[64 + lane] = o1;
}

extern "C" void kernel_launch(void* const* d_in, const int* in_sizes, int n_in,
                              void* d_out, int out_size, void* d_ws, size_t ws_size,
                              hipStream_t stream) {
    const int* char_idx  = (const int*)d_in[0];   // [B*S]
    const int* positions = (const int*)d_in[1];   // [S]
    const float* W       = (const float*)d_in[2]; // [95, 8]

    const int nrows = in_sizes[0];                // B*S = 65536
    const int S = in_sizes[1];                    // 8192

    const size_t TBL_BYTES = (size_t)NTBL * sizeof(float4);  // 194,560

    if (ws_size >= TBL_BYTES) {
        build_tbl2<<<(NTBL + 255) / 256, 256, 0, stream>>>(W, (float4*)d_ws);
        ptok_main<<<nrows / 4, 256, 0, stream>>>(
            char_idx, positions, (const f4*)d_ws, (f4*)d_out, S);
    } else {
        ptok_fused<<<nrows / 4, 256, 0, stream>>>(
            char_idx, positions, W, (float*)d_out, S);
    }
}

// Round 6
// 30.450 us; speedup vs baseline: 1.1778x; 1.0328x over previous
//
#include <hip/hip_runtime.h>

#define PI_F 3.14159265358979323846f

constexpr int ED = 128;     // embed_dim
constexpr int NCHARS = 95;
constexpr int RPB = 4;      // rows per block = 1 row per wave, 256 threads
constexpr int TSTRIDE = 16; // floats per char record (64 B)
constexpr int PP_OFF = NCHARS * TSTRIDE + 16;  // float offset of pp20 (pad-aligned)

typedef float f4 __attribute__((ext_vector_type(4)));

// ---- build: ONE block. per-char constants + 20-entry pos_phase table.
__global__ __launch_bounds__(128) void build_consts(
    const float* __restrict__ W, float* __restrict__ ws)
{
    const int t = threadIdx.x;
    if (t < NCHARS) {
        const float* p = W + t * 8;
        const float omega = p[0] * 2.0f;
        const float g = 1.0f / (1.0f + expf(-p[5]));   // sigmoid (precise)
        float* T = ws + t * TSTRIDE;
        T[0] = omega;
        T[1] = p[6] * PI_F;          // phi
        T[2] = p[1];                 // A1
        T[3] = 2.0f * p[2];          // 2*A2 (folds sin2a = 2 s c)
        T[4] = p[3];                 // A3
        T[5] = p[4];                 // beta
        T[6] = g;                    // gamma (post-sigmoid)
        T[7] = sinf(64.0f * omega);  // for angle-add j -> j+64
        T[8] = cosf(64.0f * omega);
        T[9] = expf(-64.0f * g);     // env ratio j -> j+64
        T[10] = 0.0f; T[11] = 0.0f; T[12] = 0.0f;
        T[13] = 0.0f; T[14] = 0.0f; T[15] = 0.0f;
    } else if (t >= 96 && t < 96 + 20) {
        // sin(0.1*pi*p) for integer p depends only on p mod 20 (exact)
        ws[PP_OFF + (t - 96)] = sinf((float)(t - 96) * (0.1f * PI_F));
    }
}

// ---- main: fused, 1 wave per output row, scalarized row-uniform work
__global__ __launch_bounds__(256) void ptok_main(
    const int* __restrict__ char_idx,
    const int* __restrict__ positions,
    const float* __restrict__ ws,
    f4* __restrict__ out,
    int S)
{
    const int lane = threadIdx.x & 63;
    const int row = blockIdx.x * RPB + (threadIdx.x >> 6);
    // force row-uniform chain onto the scalar pipe
    const int urow = __builtin_amdgcn_readfirstlane(row);
    const int s = urow & (S - 1);                 // S = 8192 (pow2)
    const int c = char_idx[urow];                 // uniform addr -> s_load
    const unsigned pv = (unsigned)positions[s];   // uniform addr -> s_load
    const float pp = ws[PP_OFF + (pv % 20u)];     // scalar magic-mod + s_load

    const float* T = ws + c * TSTRIDE;
    const float omega = T[0], phi = T[1];
    const float A1 = T[2], A2p = T[3], A3 = T[4];
    const float bp = T[5] * pp;                   // beta * pos_phase (uniform)
    const float g  = T[6];
    const float s64 = T[7], c64 = T[8], e64 = T[9];

    const float fj = (float)lane;
    const float a0  = fmaf(omega, fj, phi);
    const float sa0 = __sinf(a0);
    const float ca0 = __cosf(a0);
    const float env0 = __expf(-g * fj);
    // j+64 via angle addition / env ratio (no extra transcendentals)
    const float sa1 = fmaf(sa0, c64, ca0 * s64);
    const float ca1 = fmaf(ca0, c64, -sa0 * s64);
    const float env1 = env0 * e64;

    // wave = (A1 sin a + 2A2 sin a cos a + A3 sin a (3 - 4 sin^2 a)) * env
    const float t0 = sa0 * sa0;
    const float s3_0 = sa0 * fmaf(-4.0f, t0, 3.0f);
    float acc0 = A1 * sa0;
    acc0 = fmaf(A2p, sa0 * ca0, acc0);
    acc0 = fmaf(A3, s3_0, acc0);
    const float w0 = fmaf(bp, fj, acc0 * env0);

    const float t1 = sa1 * sa1;
    const float s3_1 = sa1 * fmaf(-4.0f, t1, 3.0f);
    float acc1 = A1 * sa1;
    acc1 = fmaf(A2p, sa1 * ca1, acc1);
    acc1 = fmaf(A3, s3_1, acc1);
    const float w1 = fmaf(bp, fj + 64.0f, acc1 * env1);

    // roll(wave,1): prev[j] = wave[(j-1) & 127]
    const int lm1 = (lane + 63) & 63;
    const float u0 = __shfl(w0, lm1, 64);
    const float u1 = __shfl(w1, lm1, 64);
    const float prev0 = (lane == 0) ? u1 : u0;  // j=0  -> wave[127]
    const float prev1 = (lane == 0) ? u0 : u1;  // j=64 -> wave[63]

    f4* orow = out + ((size_t)row << 7);
    f4 o0, o1;
    o0.x = w0; o0.y = prev0; o0.z = __sinf(w0); o0.w = __cosf(w0);
    o1.x = w1; o1.y = prev1; o1.z = __sinf(w1); o1.w = __cosf(w1);
    orow[lane] = o0;
    orow[64 + lane] = o1;
}

// ---- fallback (round-2 fused) if ws is unexpectedly tiny
__global__ __launch_bounds__(256) void ptok_fused(
    const int* __restrict__ char_idx,
    const int* __restrict__ positions,
    const float* __restrict__ W,
    float* __restrict__ out,
    int S)
{
    const int lane = threadIdx.x & 63;
    const int wv = threadIdx.x >> 6;
    const int row = blockIdx.x * RPB + wv;
    const int s = row & (S - 1);

    const int c = char_idx[row];
    const float4 p0 = reinterpret_cast<const float4*>(W + c * 8)[0];
    const float4 p1 = reinterpret_cast<const float4*>(W + c * 8)[1];
    const float omega = p0.x * 2.0f;
    const float A1 = p0.y, A2 = p0.z, A3 = p0.w;
    const float beta = p1.x;
    const float gamma = 1.0f / (1.0f + __expf(-p1.y));
    const float phi = p1.z * PI_F;
    const float pos_phase = __sinf((float)positions[s] * (0.1f * PI_F));

    float w01[2];
    #pragma unroll
    for (int k = 0; k < 2; ++k) {
        const float fj = (float)(lane + 64 * k);
        const float a = omega * fj + phi;
        const float sa = __sinf(a);
        const float ca = __cosf(a);
        const float wave = (A1 * sa + A2 * (2.0f * sa * ca)
                            + A3 * sa * (3.0f - 4.0f * sa * sa))
                           * __expf(-gamma * fj);
        w01[k] = wave + beta * fj * pos_phase;
    }
    const int lm1 = (lane + 63) & 63;
    const float u0 = __shfl(w01[0], lm1, 64);
    const float u1 = __shfl(w01[1], lm1, 64);
    const float prev0 = (lane == 0) ? u1 : u0;
    const float prev1 = (lane == 0) ? u0 : u1;

    float4* orow = reinterpret_cast<float4*>(out) + (size_t)row * ED;
    float4 o0, o1;
    o0.x = w01[0]; o0.y = prev0; o0.z = __sinf(w01[0]); o0.w = __cosf(w01[0]);
    o1.x = w01[1]; o1.y = prev1; o1.z = __sinf(w01[1]); o1.w = __cosf(w01[1]);
    orow[lane] = o0;
    orow[64 + lane] = o1;
}

extern "C" void kernel_launch(void* const* d_in, const int* in_sizes, int n_in,
                              void* d_out, int out_size, void* d_ws, size_t ws_size,
                              hipStream_t stream) {
    const int* char_idx  = (const int*)d_in[0];   // [B*S]
    const int* positions = (const int*)d_in[1];   // [S]
    const float* W       = (const float*)d_in[2]; // [95, 8]

    const int nrows = in_sizes[0];                // B*S = 65536
    const int S = in_sizes[1];                    // 8192

    const size_t NEED = (size_t)(PP_OFF + 20) * sizeof(float);  // ~6.3 KB

    if (ws_size >= NEED) {
        build_consts<<<1, 128, 0, stream>>>(W, (float*)d_ws);
        ptok_main<<<nrows / RPB, 256, 0, stream>>>(
            char_idx, positions, (const float*)d_ws, (f4*)d_out, S);
    } else {
        ptok_fused<<<nrows / RPB, 256, 0, stream>>>(
            char_idx, positions, W, (float*)d_out, S);
    }
}

// Round 7
// 26.635 us; speedup vs baseline: 1.3465x; 1.1432x over previous
//
#include <hip/hip_runtime.h>

#define PI_F 3.14159265358979323846f

constexpr int WPB = 4;   // waves per block (256 threads)

typedef float f4 __attribute__((ext_vector_type(4)));

__global__ __launch_bounds__(256) void ptok_persist(
    const int* __restrict__ char_idx,
    const int* __restrict__ positions,
    const float* __restrict__ W,
    f4* __restrict__ out,
    int S, int nrows, int nwaves)
{
    const int lane = threadIdx.x & 63;
    // scalar global wave id (uniform per wave)
    const int wid0 = __builtin_amdgcn_readfirstlane(
        blockIdx.x * WPB + (threadIdx.x >> 6));
    const float fj = (float)lane;
    const int lm1 = (lane + 63) & 63;

    for (int row = wid0; row < nrows; row += nwaves) {
        // ---- row-uniform (scalar pipe) ----
        const int s = row & (S - 1);               // S = 8192 (pow2)
        const int c = char_idx[row];               // s_load
        const unsigned pv = (unsigned)positions[s];// s_load
        // sin(0.1*pi*p) has exact integer period 20 -> small-angle __sinf
        const float pp = __sinf((float)(pv % 20u) * (0.1f * PI_F));

        const float* p = W + c * 8;                // s_loads (L1-hot)
        const float omega = p[0] * 2.0f;
        const float A1 = p[1];
        const float A2p = 2.0f * p[2];             // folds sin2a = 2 s c
        const float A3 = p[3];
        const float bp = p[4] * pp;                // beta * pos_phase
        const float g = 1.0f / (1.0f + __expf(-p[5]));  // sigmoid
        const float phi = p[6] * PI_F;

        // ---- per-lane: two j's (lane, lane+64) ----
        float w[2];
        #pragma unroll
        for (int k = 0; k < 2; ++k) {
            const float j = fj + 64.0f * k;
            const float a = fmaf(omega, j, phi);
            const float sa = __sinf(a);
            const float ca = __cosf(a);
            const float env = __expf(-g * j);
            // wave = (A1 sin a + 2A2 sin a cos a + A3 sin a (3-4 sin^2 a)) env
            float acc = A1 * sa;
            acc = fmaf(A2p, sa * ca, acc);
            acc = fmaf(A3, sa * fmaf(-4.0f, sa * sa, 3.0f), acc);
            w[k] = fmaf(bp, j, acc * env);
        }

        // roll(wave,1): prev[j] = wave[(j-1) & 127]
        const float u0 = __shfl(w[0], lm1, 64);
        const float u1 = __shfl(w[1], lm1, 64);
        const float prev0 = (lane == 0) ? u1 : u0;  // j=0  -> wave[127]
        const float prev1 = (lane == 0) ? u0 : u1;  // j=64 -> wave[63]

        f4* orow = out + ((size_t)row << 7);
        f4 o0, o1;
        o0.x = w[0]; o0.y = prev0; o0.z = __sinf(w[0]); o0.w = __cosf(w[0]);
        o1.x = w[1]; o1.y = prev1; o1.z = __sinf(w[1]); o1.w = __cosf(w[1]);
        orow[lane] = o0;
        orow[64 + lane] = o1;
    }
}

extern "C" void kernel_launch(void* const* d_in, const int* in_sizes, int n_in,
                              void* d_out, int out_size, void* d_ws, size_t ws_size,
                              hipStream_t stream) {
    const int* char_idx  = (const int*)d_in[0];   // [B*S]
    const int* positions = (const int*)d_in[1];   // [S]
    const float* W       = (const float*)d_in[2]; // [95, 8]

    const int nrows = in_sizes[0];                // B*S = 65536
    const int S = in_sizes[1];                    // 8192

    const int nblocks = 2048;                     // 8 blocks/CU, persistent
    const int nwaves = nblocks * WPB;             // 8192 waves, 8 rows each
    ptok_persist<<<nblocks, 256, 0, stream>>>(
        char_idx, positions, W, (f4*)d_out, S, nrows, nwaves);
}